// Round 11
// baseline (417.588 us; speedup 1.0000x reference)
//
#include <hip/hip_runtime.h>
#include <math.h>

#define DEV __device__ __forceinline__

constexpr int BB = 2, N = 2048, KK = 8;
constexpr int NODES = BB * N;          // 4096
constexpr int NPB = 8;                 // nodes per block
constexpr int TPB = 512;               // 8 waves
constexpr int NBLK = NODES / NPB;      // 512 blocks == 2/CU x 256 CU (co-resident)

typedef __attribute__((ext_vector_type(8))) short short8v;
typedef __attribute__((ext_vector_type(4))) float float4v;
union S8 { short8v v; unsigned u[4]; unsigned short s[8]; };

// ---- bool input format detection ----
DEV int bool_mode(const void* p) {
  unsigned v = *(const unsigned*)p;
  if (v == 0x3f800000u) return 2;      // float32 1.0
  if (v <= 1u) return 1;               // int32 0/1
  return 0;                            // uint8
}
DEV bool read_mask(const void* p, int i, int mode) {
  if (mode == 2) return ((const float*)p)[i] != 0.f;
  if (mode == 1) return ((const int*)p)[i] != 0;
  return ((const unsigned char*)p)[i] != 0;
}

// ---- bf16 helpers (RNE) ----
DEV unsigned short f2bf(float x) {
  unsigned u = __builtin_bit_cast(unsigned, x);
  return (unsigned short)((u + 0x7FFFu + ((u >> 16) & 1u)) >> 16);
}
DEV unsigned pk2(float a, float b) {
  return (unsigned)f2bf(a) | ((unsigned)f2bf(b) << 16);
}

// ---- swizzled bf16 tile primitives: tile[row][kk], element-swizzle kk^=(row&7)<<3
DEV short8v rdA(const unsigned short* T, int row, int kk0) {
  return *(const short8v*)&T[row * 64 + (kk0 ^ ((row & 7) << 3))];
}
DEV void stage_wT(const float* __restrict__ W, unsigned short* wt, int t) {
  const int f = t & 63, k0 = (t >> 6) * 8;
  S8 p;
  #pragma unroll
  for (int q = 0; q < 4; ++q)
    p.u[q] = pk2(W[(k0 + 2 * q) * 64 + f], W[(k0 + 2 * q + 1) * 64 + f]);
  *(short8v*)&wt[f * 64 + (k0 ^ ((f & 7) << 3))] = p.v;
}
DEV void stage_row8(unsigned short* T, int row, int kq, const float* __restrict__ g) {
  const int k0 = kq * 8;
  float4 v0 = ((const float4*)(g + k0))[0];
  float4 v1 = ((const float4*)(g + k0))[1];
  S8 p;
  p.u[0] = pk2(v0.x, v0.y); p.u[1] = pk2(v0.z, v0.w);
  p.u[2] = pk2(v1.x, v1.y); p.u[3] = pk2(v1.z, v1.w);
  *(short8v*)&T[row * 64 + (k0 ^ ((row & 7) << 3))] = p.v;
}

#define LESS(da, ja, db, jb) ((da) < (db) || ((da) == (db) && (ja) < (jb)))
#define CE(a, b)                                                              \
  {                                                                           \
    bool sw_ = LESS(nd[b], nj[b], nd[a], nj[a]);                              \
    float t_ = nd[a]; int u_ = nj[a];                                         \
    if (sw_) { nd[a] = nd[b]; nj[a] = nj[b]; nd[b] = t_; nj[b] = u_; }        \
  }

struct SEdge { float px[N], py[N], pz[N], padd[N]; };   // 32 KB (aliases Ubuf)

// device-scope sense-free barrier: one counter per use, zeroed by host memset
DEV void gbar(unsigned* bar, int idx) {
  __syncthreads();
  if (threadIdx.x == 0) {
    __threadfence();
    __hip_atomic_fetch_add(&bar[idx], 1u, __ATOMIC_RELEASE, __HIP_MEMORY_SCOPE_AGENT);
    while (__hip_atomic_load(&bar[idx], __ATOMIC_ACQUIRE,
                             __HIP_MEMORY_SCOPE_AGENT) < (unsigned)NBLK)
      __builtin_amdgcn_s_sleep(2);
    __threadfence();
  }
  __syncthreads();
}

// ================= single fused kernel =========================================
__global__ __launch_bounds__(TPB, 4) void k_all(
    const float* __restrict__ states, const void* maskp, const void* toolp,
    const float* __restrict__ a_cur, const float* __restrict__ s_delta,
    const float* __restrict__ pe_w1, const float* __restrict__ pe_b1,
    const float* __restrict__ pe_w2, const float* __restrict__ pe_b2,
    const float* __restrict__ re_w1, const float* __restrict__ re_b1,
    const float* __restrict__ re_w2, const float* __restrict__ re_b2,
    const float* __restrict__ re_w3, const float* __restrict__ re_b3,
    const float* __restrict__ rp_w, const float* __restrict__ rp_b,
    const float* __restrict__ pp_w, const float* __restrict__ pp_b,
    const float* __restrict__ pr_w1, const float* __restrict__ pr_b1,
    const float* __restrict__ pr_w2, const float* __restrict__ pr_b2,
    float* __restrict__ effA, float* __restrict__ effB,
    unsigned* __restrict__ bar, float* __restrict__ out) {
  __shared__ unsigned short wt_rp0[4096], wt_rp1[4096], wt_rp2[4096];  // 24 KB
  __shared__ char Ubuf[32768];                                         // 32 KB
  __shared__ int   sl_idx[64];
  __shared__ float sl_val[64];
  const int tid = threadIdx.x;
  const int wav = tid >> 6, lane = tid & 63;
  const int blk = blockIdx.x;
  const int node0 = blk * NPB;
  const int b = node0 >> 11;
  const int nb = node0 & ~(N - 1);
  const int mm = bool_mode(maskp), mt = bool_mode(toolp);

  // ---------- phase 0: persistent rp_w bf16 tiles (rows 0-63 / 64-127 / 128-191)
  stage_wT(rp_w,        wt_rp0, tid);
  stage_wT(rp_w + 4096, wt_rp1, tid);
  stage_wT(rp_w + 8192, wt_rp2, tid);

  // ---------- phase 1: 8-NN edges (proven scan), results to LDS only ----------
  {
    SEdge* se = (SEdge*)Ubuf;
    for (int j = tid; j < N; j += TPB) {
      const float* s = states + (size_t)(b * N + j) * 3;
      se->px[j] = s[0]; se->py[j] = s[1]; se->pz[j] = s[2];
      se->padd[j] = read_mask(maskp, b * N + j, mm) ? 0.f : 1e10f;
    }
    __syncthreads();
    const int node = node0 + wav;
    const int i = node & (N - 1);
    const bool mi = read_mask(maskp, node, mm);
    const bool ti = read_mask(toolp, node, mt);   // tool receivers: no edges
    float td[KK]; int tj[KK];
    #pragma unroll
    for (int k = 0; k < KK; ++k) { td[k] = 3.0e38f; tj[k] = 0; }
    if (mi && !ti) {
      const float sx = se->px[i], sy = se->py[i], sz = se->pz[i];
      #pragma unroll 4
      for (int it = 0; it < N / 64; ++it) {
        int j = lane + it * 64;
        float dx = sx - se->px[j], dy = sy - se->py[j], dz = sz - se->pz[j];
        float dis = __fadd_rn(__fadd_rn(__fmul_rn(dx, dx), __fmul_rn(dy, dy)),
                              __fmul_rn(dz, dz));
        float dd = __fadd_rn(dis, se->padd[j]);     // masked -> exactly 1e10
        if (dd < td[KK - 1]) {                      // strict < == stable
          float cd = dd; int cj = j;
          #pragma unroll
          for (int m = 0; m < KK; ++m) {
            bool sw = cd < td[m];
            float od = td[m]; int oj = tj[m];
            td[m] = sw ? cd : od; tj[m] = sw ? cj : oj;
            cd = sw ? od : cd;   cj = sw ? oj : cj;
          }
        }
      }
      #pragma unroll
      for (int m = 1; m < 64; m <<= 1) {
        float pd[KK]; int pj[KK];
        #pragma unroll
        for (int r = 0; r < KK; ++r) {
          pd[r] = __shfl_xor(td[r], m);
          pj[r] = __shfl_xor(tj[r], m);
        }
        float nd[KK]; int nj[KK];
        #pragma unroll
        for (int r = 0; r < KK; ++r) {
          float ad = td[r]; int aj = tj[r];
          float bd = pd[KK - 1 - r]; int bj = pj[KK - 1 - r];
          bool tb = LESS(bd, bj, ad, aj);
          nd[r] = tb ? bd : ad; nj[r] = tb ? bj : aj;
        }
        CE(0, 4) CE(1, 5) CE(2, 6) CE(3, 7)
        CE(0, 2) CE(1, 3) CE(4, 6) CE(5, 7)
        CE(0, 1) CE(2, 3) CE(4, 5) CE(6, 7)
        #pragma unroll
        for (int r = 0; r < KK; ++r) { td[r] = nd[r]; tj[r] = nj[r]; }
      }
    }
    if (lane == 0) {
      const float T2 = (float)(0.12 * 0.12);
      const bool ok = mi && !ti;
      #pragma unroll
      for (int k = 0; k < KK; ++k) {
        sl_idx[wav * KK + k] = tj[k];
        sl_val[wav * KK + k] = (ok && td[k] < T2) ? 1.f : 0.f;
      }
    }
    __syncthreads();                                // SEdge dead after this
  }

  // ---------- phase 2: node encoder (exact f32); pc/ev live in registers ------
  float pc, ev;                                     // p_const / eff for (wav,lane)
  {
    unsigned short* wt_enc0 = (unsigned short*)(Ubuf + 16384);
    unsigned short* wt_enc1 = (unsigned short*)(Ubuf + 24576);
    stage_wT(re_w2, wt_enc0, tid);                  // consumed in phase 3
    stage_wT(re_w3, wt_enc1, tid);
    float* hb = (float*)Ubuf;                       // [64 f][9], 2.25 KB
    const int nd = node0 + wav;
    const int i = nd & (N - 1);
    const int f = lane;
    float sd[9];
    #pragma unroll
    for (int k = 0; k < 9; ++k) sd[k] = s_delta[(b * 9 + k) * N + i];
    const float a = a_cur[nd];
    float x = pe_b1[f];
    #pragma unroll
    for (int k = 0; k < 9; ++k) x = fmaf(sd[k], pe_w1[k * 64 + f], x);
    x = fmaf(a, pe_w1[576 + f] + pe_w1[640 + f] + pe_w1[704 + f], x);
    x = fmaxf(x, 0.f);
    hb[f * 9 + wav] = x;
    __syncthreads();
    float y = pe_b2[f];
    #pragma unroll 4
    for (int k = 0; k < 64; ++k) y = fmaf(hb[k * 9 + wav], pe_w2[k * 64 + f], y);
    y = fmaxf(y, 0.f);
    effA[(size_t)nd * 64 + f] = y;                  // p_enc == initial effect
    ev = y;
    __syncthreads();
    hb[f * 9 + wav] = y;
    __syncthreads();
    float z = pp_b[f];
    #pragma unroll 4
    for (int k = 0; k < 64; ++k) z = fmaf(hb[k * 9 + wav], pp_w[k * 64 + f], z);
    pc = z;                                         // pp_b + p_enc @ pp_w[0:64]
    __syncthreads();                                // hb dead
  }

  // ---------- phase 3: edge encoder (MFMA), rel_const -> LDS relC -------------
  {
    unsigned short* A0 = (unsigned short*)Ubuf;
    unsigned short* A1 = (unsigned short*)(Ubuf + 8192);
    unsigned short* wt_enc0 = (unsigned short*)(Ubuf + 16384);
    unsigned short* wt_enc1 = (unsigned short*)(Ubuf + 24576);
    float* relC = (float*)(Ubuf + 16384);           // overwrites wt_enc at L4
    const int f0 = __builtin_amdgcn_readfirstlane(wav * 8);
    const int col = lane;
    const int nd = node0 + (col >> 3);
    const int j = nb + sl_idx[col];
    const float a_r = a_cur[nd], a_s = a_cur[j];
    const float dx = states[nd * 3]     - states[j * 3];
    const float dy = states[nd * 3 + 1] - states[j * 3 + 1];
    const float dz = states[nd * 3 + 2] - states[j * 3 + 2];
    float t[8];
    #pragma unroll
    for (int u = 0; u < 8; ++u) {
      const int f = f0 + u;
      float x = re_b1[f];
      x = fmaf(a_r, re_w1[f], x);
      x = fmaf(a_s, re_w1[64 + f], x);
      x = fmaf(dx, re_w1[128 + f], x);
      x = fmaf(dy, re_w1[192 + f], x);
      x = fmaf(dz, re_w1[256 + f], x);
      t[u] = fmaxf(x, 0.f);
    }
    #pragma unroll
    for (int u = 0; u < 8; u += 2) {
      int idx = col * 64 + ((f0 + u) ^ ((col & 7) << 3));
      *(unsigned*)&A0[idx] = pk2(t[u], t[u + 1]);
    }
    __syncthreads();
    const int m = wav & 3, h = wav >> 2;
    const int rowA = m * 16 + (lane & 15);
    const int fc0 = (2 * h) * 16 + (lane & 15), fc1 = fc0 + 16;
    const unsigned long long vm = __ballot(sl_val[lane] != 0.f);
    // L2: A0 x re_w2 (+b, relu) -> A1
    {
      float b0 = re_b2[fc0], b1 = re_b2[fc1];
      float4v c0 = {b0, b0, b0, b0}, c1 = {b1, b1, b1, b1};
      #pragma unroll
      for (int ks = 0; ks < 2; ++ks) {
        const int kk0 = ks * 32 + (lane >> 4) * 8;
        short8v a  = rdA(A0, rowA, kk0);
        short8v w0 = rdA(wt_enc0, fc0, kk0);
        short8v w1 = rdA(wt_enc0, fc1, kk0);
        c0 = __builtin_amdgcn_mfma_f32_16x16x32_bf16(a, w0, c0, 0, 0, 0);
        c1 = __builtin_amdgcn_mfma_f32_16x16x32_bf16(a, w1, c1, 0, 0, 0);
      }
      #pragma unroll
      for (int r = 0; r < 4; ++r) {
        int slot = m * 16 + (lane >> 4) * 4 + r;
        A1[slot * 64 + (fc0 ^ ((slot & 7) << 3))] = f2bf(fmaxf(c0[r], 0.f));
        A1[slot * 64 + (fc1 ^ ((slot & 7) << 3))] = f2bf(fmaxf(c1[r], 0.f));
      }
    }
    __syncthreads();
    // L3: A1 x re_w3 (+b, relu) -> A0
    {
      float b0 = re_b3[fc0], b1 = re_b3[fc1];
      float4v c0 = {b0, b0, b0, b0}, c1 = {b1, b1, b1, b1};
      #pragma unroll
      for (int ks = 0; ks < 2; ++ks) {
        const int kk0 = ks * 32 + (lane >> 4) * 8;
        short8v a  = rdA(A1, rowA, kk0);
        short8v w0 = rdA(wt_enc1, fc0, kk0);
        short8v w1 = rdA(wt_enc1, fc1, kk0);
        c0 = __builtin_amdgcn_mfma_f32_16x16x32_bf16(a, w0, c0, 0, 0, 0);
        c1 = __builtin_amdgcn_mfma_f32_16x16x32_bf16(a, w1, c1, 0, 0, 0);
      }
      #pragma unroll
      for (int r = 0; r < 4; ++r) {
        int slot = m * 16 + (lane >> 4) * 4 + r;
        A0[slot * 64 + (fc0 ^ ((slot & 7) << 3))] = f2bf(fmaxf(c0[r], 0.f));
        A0[slot * 64 + (fc1 ^ ((slot & 7) << 3))] = f2bf(fmaxf(c1[r], 0.f));
      }
    }
    __syncthreads();
    // L4: A0 x rp_w[0:64] (+rp_b, no relu), x valid -> relC (LDS)
    {
      float b0 = rp_b[fc0], b1 = rp_b[fc1];
      float4v c0 = {b0, b0, b0, b0}, c1 = {b1, b1, b1, b1};
      #pragma unroll
      for (int ks = 0; ks < 2; ++ks) {
        const int kk0 = ks * 32 + (lane >> 4) * 8;
        short8v a  = rdA(A0, rowA, kk0);
        short8v w0 = rdA(wt_rp0, fc0, kk0);
        short8v w1 = rdA(wt_rp0, fc1, kk0);
        c0 = __builtin_amdgcn_mfma_f32_16x16x32_bf16(a, w0, c0, 0, 0, 0);
        c1 = __builtin_amdgcn_mfma_f32_16x16x32_bf16(a, w1, c1, 0, 0, 0);
      }
      #pragma unroll
      for (int r = 0; r < 4; ++r) {
        int slot = m * 16 + (lane >> 4) * 4 + r;
        float v = (float)((vm >> slot) & 1ull);
        relC[slot * 64 + fc0] = c0[r] * v;
        relC[slot * 64 + fc1] = c1[r] * v;
      }
    }
  }

  gbar(bar, 0);   // effA (initial effects) visible device-wide

  // ---------- phases 4-6: three propagation steps -----------------------------
  auto prop = [&](const float* __restrict__ effIn, float* __restrict__ effOut) {
    unsigned short* AS = (unsigned short*)Ubuf;            // [64 slots][64] bf16
    unsigned short* EN = (unsigned short*)(Ubuf + 8192);   // [8 nodes][64] bf16
    float* agg = (float*)(Ubuf + 9216);                    // [8][64] f32
    float* relC = (float*)(Ubuf + 16384);                  // persists all steps
    {
      const int slot = tid >> 3, kq = tid & 7;
      const int j = nb + sl_idx[slot];
      stage_row8(AS, slot, kq, effIn + (size_t)j * 64);    // sender gather
    }
    EN[wav * 64 + (lane ^ ((wav & 7) << 3))] = f2bf(ev);   // receiver from reg
    const unsigned long long vm = __ballot(sl_val[lane] != 0.f);
    __syncthreads();
    {
      const int m = wav & 3, h = wav >> 2;
      const int rowA = m * 16 + (lane & 15);
      const int nodeR = rowA >> 3;
      const int fc0 = (2 * h) * 16 + (lane & 15), fc1 = fc0 + 16;
      float4v c0, c1;
      #pragma unroll
      for (int r = 0; r < 4; ++r) {
        int slot = m * 16 + (lane >> 4) * 4 + r;
        c0[r] = relC[slot * 64 + fc0];
        c1[r] = relC[slot * 64 + fc1];
      }
      #pragma unroll
      for (int ks = 0; ks < 2; ++ks) {
        const int kk0 = ks * 32 + (lane >> 4) * 8;
        short8v aR = rdA(EN, nodeR, kk0);
        short8v aS = rdA(AS, rowA, kk0);
        short8v w10 = rdA(wt_rp1, fc0, kk0);
        short8v w11 = rdA(wt_rp1, fc1, kk0);
        short8v w20 = rdA(wt_rp2, fc0, kk0);
        short8v w21 = rdA(wt_rp2, fc1, kk0);
        c0 = __builtin_amdgcn_mfma_f32_16x16x32_bf16(aR, w10, c0, 0, 0, 0);
        c1 = __builtin_amdgcn_mfma_f32_16x16x32_bf16(aR, w11, c1, 0, 0, 0);
        c0 = __builtin_amdgcn_mfma_f32_16x16x32_bf16(aS, w20, c0, 0, 0, 0);
        c1 = __builtin_amdgcn_mfma_f32_16x16x32_bf16(aS, w21, c1, 0, 0, 0);
      }
      float s0 = 0.f, s1 = 0.f;
      #pragma unroll
      for (int r = 0; r < 4; ++r) {
        int slot = m * 16 + (lane >> 4) * 4 + r;
        float v = (float)((vm >> slot) & 1ull);
        s0 += fmaxf(c0[r], 0.f) * v;
        s1 += fmaxf(c1[r], 0.f) * v;
      }
      s0 += __shfl_xor(s0, 16);
      s1 += __shfl_xor(s1, 16);
      if (((lane >> 4) & 1) == 0) {
        const int an = m * 2 + (lane >> 5);
        agg[an * 64 + fc0] = s0;
        agg[an * 64 + fc1] = s1;
      }
    }
    __syncthreads();
    float o = pc;                                          // wave=node, lane=f
    #pragma unroll 4
    for (int g = 0; g < 64; ++g)
      o = fmaf(agg[wav * 64 + g], pp_w[4096 + g * 64 + lane], o);
    float ov = fmaxf(o + ev, 0.f);
    if (effOut) effOut[(size_t)(node0 + wav) * 64 + lane] = ov;
    ev = ov;
    __syncthreads();                                       // AS/EN/agg reuse
  };

  prop(effA, effB);
  gbar(bar, 1);
  prop(effB, effA);
  gbar(bar, 2);
  prop(effA, nullptr);                                     // final step stays local

  // ---------- phase 7: predictor head + residual ------------------------------
  {
    float* agg = (float*)(Ubuf + 9216);
    agg[wav * 64 + lane] = ev;                             // final eff [node][f]
    __syncthreads();
    float hh = pr_b1[lane];
    #pragma unroll 4
    for (int k = 0; k < 64; ++k)
      hh = fmaf(agg[wav * 64 + k], pr_w1[k * 64 + lane], hh);
    hh = fmaxf(hh, 0.f);
    float p0 = hh * pr_w2[lane * 3];
    float p1 = hh * pr_w2[lane * 3 + 1];
    float p2 = hh * pr_w2[lane * 3 + 2];
    #pragma unroll
    for (int m = 1; m < 64; m <<= 1) {
      p0 += __shfl_xor(p0, m);
      p1 += __shfl_xor(p1, m);
      p2 += __shfl_xor(p2, m);
    }
    if (lane == 0) {
      const int onode = node0 + wav;
      out[onode * 3]     = states[onode * 3]     + p0 + pr_b2[0];
      out[onode * 3 + 1] = states[onode * 3 + 1] + p1 + pr_b2[1];
      out[onode * 3 + 2] = states[onode * 3 + 2] + p2 + pr_b2[2];
    }
  }
}

extern "C" void kernel_launch(void* const* d_in, const int* in_sizes, int n_in,
                              void* d_out, int out_size, void* d_ws, size_t ws_size,
                              hipStream_t stream) {
  const float* states  = (const float*)d_in[0];
  const float* a_cur   = (const float*)d_in[1];
  const float* s_delta = (const float*)d_in[2];
  const void*  maskp   = d_in[3];
  const void*  toolp   = d_in[4];
  const float* pe_w1 = (const float*)d_in[6];
  const float* pe_b1 = (const float*)d_in[7];
  const float* pe_w2 = (const float*)d_in[8];
  const float* pe_b2 = (const float*)d_in[9];
  const float* re_w1 = (const float*)d_in[10];
  const float* re_b1 = (const float*)d_in[11];
  const float* re_w2 = (const float*)d_in[12];
  const float* re_b2 = (const float*)d_in[13];
  const float* re_w3 = (const float*)d_in[14];
  const float* re_b3 = (const float*)d_in[15];
  const float* rp_w  = (const float*)d_in[16];
  const float* rp_b  = (const float*)d_in[17];
  const float* pp_w  = (const float*)d_in[18];
  const float* pp_b  = (const float*)d_in[19];
  const float* pr_w1 = (const float*)d_in[20];
  const float* pr_b1 = (const float*)d_in[21];
  const float* pr_w2 = (const float*)d_in[22];
  const float* pr_b2 = (const float*)d_in[23];

  char* w = (char*)d_ws;
  float* effA = (float*)w; w += (size_t)NODES * 64 * 4;
  float* effB = (float*)w; w += (size_t)NODES * 64 * 4;
  unsigned* bar = (unsigned*)w;

  hipMemsetAsync(bar, 0, 4 * sizeof(unsigned), stream);
  k_all<<<NBLK, TPB, 0, stream>>>(states, maskp, toolp, a_cur, s_delta,
      pe_w1, pe_b1, pe_w2, pe_b2, re_w1, re_b1, re_w2, re_b2, re_w3, re_b3,
      rp_w, rp_b, pp_w, pp_b, pr_w1, pr_b1, pr_w2, pr_b2,
      effA, effB, bar, (float*)d_out);
}